// Round 1
// baseline (711.345 us; speedup 1.0000x reference)
//
#include <hip/hip_runtime.h>

// ---------------------------------------------------------------------------
// Types / helpers
// ---------------------------------------------------------------------------
typedef __bf16 bf16x8 __attribute__((ext_vector_type(8)));
typedef float  f32x4  __attribute__((ext_vector_type(4)));
typedef short  s16x8  __attribute__((ext_vector_type(8)));
typedef short  s16x4  __attribute__((ext_vector_type(4)));

__device__ __forceinline__ unsigned short f2b(float f) {
  unsigned int u = __float_as_uint(f);
  u += 0x7fffu + ((u >> 16) & 1u);           // round-to-nearest-even
  return (unsigned short)(u >> 16);
}
__device__ __forceinline__ float b2f(unsigned short h) {
  return __uint_as_float(((unsigned int)h) << 16);
}

#define F4C(v, i) ((i) == 0 ? (v).x : (i) == 1 ? (v).y : (i) == 2 ? (v).z : (v).w)

// ---------------------------------------------------------------------------
// Weight transpose: in (R x C) f32 row-major  ->  out (C x R) bf16 row-major
// ---------------------------------------------------------------------------
__global__ __launch_bounds__(256) void transpose_w(const float* __restrict__ in,
                                                   unsigned short* __restrict__ out,
                                                   int R, int C) {
  __shared__ float t[32][33];
  int c0 = blockIdx.x * 32, r0 = blockIdx.y * 32;
  int tx = threadIdx.x & 31, ty = threadIdx.x >> 5;  // 32 x 8
  for (int i = ty; i < 32; i += 8)
    t[i][tx] = in[(size_t)(r0 + i) * C + (c0 + tx)];
  __syncthreads();
  for (int i = ty; i < 32; i += 8)
    out[(size_t)(c0 + i) * R + (r0 + tx)] = f2b(t[tx][i]);
}

// ---------------------------------------------------------------------------
// LayerNorm over last dim (f32 in -> bf16 out). One block per row, 256 thr.
// ---------------------------------------------------------------------------
__global__ __launch_bounds__(256) void ln_kernel(const float* __restrict__ in,
                                                 const float* __restrict__ g,
                                                 const float* __restrict__ b,
                                                 unsigned short* __restrict__ out,
                                                 int cols) {
  int row = blockIdx.x;
  const float* x = in + (size_t)row * cols;
  float s = 0.f, s2 = 0.f;
  for (int c = threadIdx.x * 4; c < cols; c += 1024) {
    float4 v = *(const float4*)(x + c);
    s  += v.x + v.y + v.z + v.w;
    s2 += v.x * v.x + v.y * v.y + v.z * v.z + v.w * v.w;
  }
#pragma unroll
  for (int o = 32; o > 0; o >>= 1) { s += __shfl_down(s, o); s2 += __shfl_down(s2, o); }
  __shared__ float rs[4], rs2[4];
  int w = threadIdx.x >> 6;
  if ((threadIdx.x & 63) == 0) { rs[w] = s; rs2[w] = s2; }
  __syncthreads();
  s  = rs[0] + rs[1] + rs[2] + rs[3];
  s2 = rs2[0] + rs2[1] + rs2[2] + rs2[3];
  float inv  = 1.f / (float)cols;
  float mean = s * inv;
  float var  = s2 * inv - mean * mean;
  float rstd = rsqrtf(var + 1e-5f);
  unsigned short* outp = out + (size_t)row * cols;
  for (int c = threadIdx.x * 4; c < cols; c += 1024) {
    float4 v = *(const float4*)(x + c);
    ushort4 ov;
    ov.x = f2b((v.x - mean) * rstd * g[c + 0] + b[c + 0]);
    ov.y = f2b((v.y - mean) * rstd * g[c + 1] + b[c + 1]);
    ov.z = f2b((v.z - mean) * rstd * g[c + 2] + b[c + 2]);
    ov.w = f2b((v.w - mean) * rstd * g[c + 3] + b[c + 3]);
    *(ushort4*)(outp + c) = ov;
  }
}

// ---------------------------------------------------------------------------
// bf16 MFMA GEMM, 128x128 tile, BK=32, 4 waves (2x2 of 64x64 wave tiles).
// A: (M x K) bf16 row-major.  Bt: (N x K) bf16 row-major (pre-transposed W).
// Epilogue template: bias / gelu / residual-add(f32) / write f32 / write bf16.
// ---------------------------------------------------------------------------
__device__ __forceinline__ void gload_lds16(const unsigned short* g, unsigned short* l) {
  __builtin_amdgcn_global_load_lds((const __attribute__((address_space(1))) void*)g,
                                   (__attribute__((address_space(3))) void*)l, 16, 0, 0);
}

template <int BIAS, int GELU, int RES, int WF32, int WBF16>
__global__ __launch_bounds__(256) void gemm128(const unsigned short* __restrict__ A,
                                               const unsigned short* __restrict__ Bt,
                                               float* __restrict__ Cf,
                                               unsigned short* __restrict__ Cb,
                                               const float* __restrict__ bias,
                                               const float* __restrict__ res,
                                               int M, int N, int K) {
  __shared__ unsigned short lA[2][128 * 32];
  __shared__ unsigned short lB[2][128 * 32];
  const int tid = threadIdx.x;
  const int w = tid >> 6, l = tid & 63;
  const int m0 = blockIdx.x * 128, n0 = blockIdx.y * 128;
  const int wm = w >> 1, wn = w & 1;
  // staging: wave w covers tile rows [w*32, w*32+32), 2 instrs of 16 rows each
  const int srow = w * 32 + (l >> 2);
  const int scol = (l & 3) * 8;
  const size_t aBase = (size_t)(m0 + srow) * K + scol;
  const size_t bBase = (size_t)(n0 + srow) * K + scol;

  auto stage = [&](int kt, int buf) {
    const unsigned short* ga = A + aBase + (size_t)kt * 32;
    const unsigned short* gb = Bt + bBase + (size_t)kt * 32;
    unsigned short* la = &lA[buf][(w * 32) * 32];
    unsigned short* lb = &lB[buf][(w * 32) * 32];
    gload_lds16(ga, la);
    gload_lds16(ga + (size_t)16 * K, la + 16 * 32);
    gload_lds16(gb, lb);
    gload_lds16(gb + (size_t)16 * K, lb + 16 * 32);
  };

  f32x4 acc[4][4];
  f32x4 zz = {0.f, 0.f, 0.f, 0.f};
#pragma unroll
  for (int i = 0; i < 4; ++i)
#pragma unroll
    for (int j = 0; j < 4; ++j) acc[i][j] = zz;

  stage(0, 0);
  __syncthreads();
  const int KT = K >> 5;
  const int rl = l & 15, kb = l >> 4;
  for (int kt = 0; kt < KT; ++kt) {
    int buf = kt & 1;
    if (kt + 1 < KT) stage(kt + 1, buf ^ 1);
    bf16x8 af[4], bfr[4];
    const unsigned short* pA = lA[buf];
    const unsigned short* pB = lB[buf];
#pragma unroll
    for (int f = 0; f < 4; ++f) {
      af[f]  = *(const bf16x8*)(pA + (wm * 64 + f * 16 + rl) * 32 + kb * 8);
      bfr[f] = *(const bf16x8*)(pB + (wn * 64 + f * 16 + rl) * 32 + kb * 8);
    }
#pragma unroll
    for (int mf = 0; mf < 4; ++mf)
#pragma unroll
      for (int nf = 0; nf < 4; ++nf)
        acc[mf][nf] = __builtin_amdgcn_mfma_f32_16x16x32_bf16(af[mf], bfr[nf], acc[mf][nf], 0, 0, 0);
    __syncthreads();
  }

  // epilogue: D[row][col], col = lane&15, row = (lane>>4)*4 + r   (m89 layout)
#pragma unroll
  for (int mf = 0; mf < 4; ++mf) {
#pragma unroll
    for (int nf = 0; nf < 4; ++nf) {
#pragma unroll
      for (int r = 0; r < 4; ++r) {
        int row = m0 + wm * 64 + mf * 16 + kb * 4 + r;
        int col = n0 + wn * 64 + nf * 16 + rl;
        float v = acc[mf][nf][r];
        if (BIAS) v += bias[col];
        if (GELU) {
          float t2 = 1.5957691f * (v + 0.044715f * v * v * v);  // 2*z
          float e = __expf(fminf(t2, 60.f));
          v = v * e / (e + 1.f);                                 // v*0.5*(1+tanh z)
        }
        if (RES) v += res[(size_t)row * N + col];
        if (WF32) Cf[(size_t)row * N + col] = v;
        if (WBF16) Cb[(size_t)row * N + col] = f2b(v);
      }
    }
  }
}

// ---------------------------------------------------------------------------
// Flash-style attention, fp32 compute, bf16 I/O.
// Q: (B,1024,1024) bf16, K/V: (B,576,1024) bf16, O: (B,1024,1024) bf16.
// Block: 64 queries of one (b,h). 9 key tiles of 64, online softmax.
// ---------------------------------------------------------------------------
__global__ __launch_bounds__(256) void attn_kernel(const unsigned short* __restrict__ Qb,
                                                   const unsigned short* __restrict__ Kb,
                                                   const unsigned short* __restrict__ Vb,
                                                   unsigned short* __restrict__ Ob) {
  __shared__ __align__(16) float Qs[64][68];
  __shared__ __align__(16) float Ks[64][68];
  __shared__ __align__(16) float Ss[64][68];
  __shared__ __align__(16) unsigned short Vs[64][72];
  __shared__ float alphaS[64], lS[64];

  const int t = threadIdx.x;
  const int b = blockIdx.z, h = blockIdx.y;
  const int q0 = blockIdx.x * 64;
  const int lrow = t >> 2, lcol = (t & 3) * 16;

  {  // load Q tile (64 x 64) -> f32 LDS
    const unsigned short* src = Qb + ((size_t)(b * 1024 + q0 + lrow) * 1024 + h * 64 + lcol);
    s16x8 v0 = *(const s16x8*)src;
    s16x8 v1 = *(const s16x8*)(src + 8);
#pragma unroll
    for (int j = 0; j < 8; ++j) {
      Qs[lrow][lcol + j]     = b2f((unsigned short)v0[j]);
      Qs[lrow][lcol + 8 + j] = b2f((unsigned short)v1[j]);
    }
  }

  const int qg = t >> 4, kg = t & 15;  // 16 q-groups x 16 k(or d)-groups
  float m_run = -1e30f, l_run = 0.f;   // valid for t<64
  float O[4][4];
#pragma unroll
  for (int i = 0; i < 4; ++i)
#pragma unroll
    for (int j = 0; j < 4; ++j) O[i][j] = 0.f;

  for (int kt = 0; kt < 9; ++kt) {
    const int k0 = kt * 64;
    {  // load K (->f32) and V (bf16) tiles
      const unsigned short* ks = Kb + ((size_t)(b * 576 + k0 + lrow) * 1024 + h * 64 + lcol);
      s16x8 v0 = *(const s16x8*)ks;
      s16x8 v1 = *(const s16x8*)(ks + 8);
#pragma unroll
      for (int j = 0; j < 8; ++j) {
        Ks[lrow][lcol + j]     = b2f((unsigned short)v0[j]);
        Ks[lrow][lcol + 8 + j] = b2f((unsigned short)v1[j]);
      }
      const unsigned short* vsrc = Vb + ((size_t)(b * 576 + k0 + lrow) * 1024 + h * 64 + lcol);
      *(s16x8*)&Vs[lrow][lcol]     = *(const s16x8*)vsrc;
      *(s16x8*)&Vs[lrow][lcol + 8] = *(const s16x8*)(vsrc + 8);
    }
    __syncthreads();

    // S tile: thread computes 4q x 4k
    float sa[4][4];
#pragma unroll
    for (int i = 0; i < 4; ++i)
#pragma unroll
      for (int j = 0; j < 4; ++j) sa[i][j] = 0.f;
    for (int d0 = 0; d0 < 64; d0 += 4) {
      float4 qv[4], kv[4];
#pragma unroll
      for (int i = 0; i < 4; ++i) qv[i] = *(const float4*)&Qs[qg * 4 + i][d0];
#pragma unroll
      for (int j = 0; j < 4; ++j) kv[j] = *(const float4*)&Ks[kg * 4 + j][d0];
#pragma unroll
      for (int i = 0; i < 4; ++i)
#pragma unroll
        for (int j = 0; j < 4; ++j)
          sa[i][j] += qv[i].x * kv[j].x + qv[i].y * kv[j].y + qv[i].z * kv[j].z + qv[i].w * kv[j].w;
    }
#pragma unroll
    for (int i = 0; i < 4; ++i) {
      float4 sv = make_float4(sa[i][0] * 0.125f, sa[i][1] * 0.125f, sa[i][2] * 0.125f, sa[i][3] * 0.125f);
      *(float4*)&Ss[qg * 4 + i][kg * 4] = sv;
    }
    __syncthreads();

    if (t < 64) {  // online softmax for row t
      float rm = -1e30f;
      for (int c = 0; c < 64; c += 4) {
        float4 v = *(const float4*)&Ss[t][c];
        rm = fmaxf(rm, fmaxf(fmaxf(v.x, v.y), fmaxf(v.z, v.w)));
      }
      float mn = fmaxf(m_run, rm);
      float al = __expf(m_run - mn);
      float rsum = 0.f;
      for (int c = 0; c < 64; c += 4) {
        float4 v = *(const float4*)&Ss[t][c];
        v.x = __expf(v.x - mn); v.y = __expf(v.y - mn);
        v.z = __expf(v.z - mn); v.w = __expf(v.w - mn);
        rsum += v.x + v.y + v.z + v.w;
        *(float4*)&Ss[t][c] = v;
      }
      l_run = l_run * al + rsum;
      m_run = mn;
      alphaS[t] = al;
    }
    __syncthreads();

    {  // rescale + PV: thread owns 4q x 4d (dg == kg)
      float al[4];
#pragma unroll
      for (int i = 0; i < 4; ++i) al[i] = alphaS[qg * 4 + i];
#pragma unroll
      for (int i = 0; i < 4; ++i)
#pragma unroll
        for (int j = 0; j < 4; ++j) O[i][j] *= al[i];
      for (int k = 0; k < 64; k += 4) {
        float4 pv[4];
#pragma unroll
        for (int i = 0; i < 4; ++i) pv[i] = *(const float4*)&Ss[qg * 4 + i][k];
#pragma unroll
        for (int kk = 0; kk < 4; ++kk) {
          s16x4 vr = *(const s16x4*)&Vs[k + kk][kg * 4];
          float v0 = b2f((unsigned short)vr[0]);
          float v1 = b2f((unsigned short)vr[1]);
          float v2 = b2f((unsigned short)vr[2]);
          float v3 = b2f((unsigned short)vr[3]);
#pragma unroll
          for (int i = 0; i < 4; ++i) {
            float p = F4C(pv[i], kk);
            O[i][0] += p * v0; O[i][1] += p * v1; O[i][2] += p * v2; O[i][3] += p * v3;
          }
        }
      }
    }
    __syncthreads();
  }

  if (t < 64) lS[t] = l_run;
  __syncthreads();
#pragma unroll
  for (int i = 0; i < 4; ++i) {
    float linv = 1.f / lS[qg * 4 + i];
    unsigned short* dst = Ob + ((size_t)(b * 1024 + q0 + qg * 4 + i) * 1024 + h * 64 + kg * 4);
    ushort4 ov;
    ov.x = f2b(O[i][0] * linv);
    ov.y = f2b(O[i][1] * linv);
    ov.z = f2b(O[i][2] * linv);
    ov.w = f2b(O[i][3] * linv);
    *(ushort4*)dst = ov;
  }
}

// ---------------------------------------------------------------------------
// Launch
// ---------------------------------------------------------------------------
extern "C" void kernel_launch(void* const* d_in, const int* in_sizes, int n_in,
                              void* d_out, int out_size, void* d_ws, size_t ws_size,
                              hipStream_t stream) {
  const float* grid_in = (const float*)d_in[0];   // (8,24,24,1024)
  const float* qpos    = (const float*)d_in[1];   // (8,1024,512)
  const float* Wq      = (const float*)d_in[2];   // (512,1024)
  const float* Wk      = (const float*)d_in[3];   // (1024,1024)
  const float* Wv      = (const float*)d_in[4];
  const float* Wo      = (const float*)d_in[5];
  const float* g_grid  = (const float*)d_in[6];
  const float* b_grid  = (const float*)d_in[7];
  const float* g_q     = (const float*)d_in[8];
  const float* b_q     = (const float*)d_in[9];
  const float* g_mlp   = (const float*)d_in[10];
  const float* b_mlp   = (const float*)d_in[11];
  const float* W1      = (const float*)d_in[12];  // (1024,4096)
  const float* b1      = (const float*)d_in[13];
  const float* W2      = (const float*)d_in[14];  // (4096,1024)
  const float* b2      = (const float*)d_in[15];

  char* ws = (char*)d_ws;
  size_t off = 0;
  auto alloc = [&](size_t bytes) -> void* {
    void* p = ws + off;
    off = (off + bytes + 255) & ~(size_t)255;
    return p;
  };

  unsigned short* Wqt = (unsigned short*)alloc((size_t)1024 * 512 * 2);
  unsigned short* Wkt = (unsigned short*)alloc((size_t)1024 * 1024 * 2);
  unsigned short* Wvt = (unsigned short*)alloc((size_t)1024 * 1024 * 2);
  unsigned short* Wot = (unsigned short*)alloc((size_t)1024 * 1024 * 2);
  unsigned short* W1t = (unsigned short*)alloc((size_t)4096 * 1024 * 2);
  unsigned short* W2t = (unsigned short*)alloc((size_t)1024 * 4096 * 2);
  unsigned short* gn  = (unsigned short*)alloc((size_t)4608 * 1024 * 2);
  unsigned short* qn  = (unsigned short*)alloc((size_t)8192 * 512 * 2);
  unsigned short* Kb  = (unsigned short*)alloc((size_t)4608 * 1024 * 2);
  unsigned short* Vb  = (unsigned short*)alloc((size_t)4608 * 1024 * 2);
  float*          Qf  = (float*)alloc((size_t)8192 * 1024 * 4);
  unsigned short* Qbf = (unsigned short*)alloc((size_t)8192 * 1024 * 2);
  unsigned short* atb = (unsigned short*)alloc((size_t)8192 * 1024 * 2);
  float*          xf  = (float*)alloc((size_t)8192 * 1024 * 4);
  unsigned short* xnb = (unsigned short*)alloc((size_t)8192 * 1024 * 2);
  unsigned short* hb  = (unsigned short*)alloc((size_t)8192 * 4096 * 2);
  (void)ws_size; (void)in_sizes; (void)n_in; (void)out_size;

  // weight transposes (f32 -> bf16, N-major)
  transpose_w<<<dim3(32, 16), 256, 0, stream>>>(Wq, Wqt, 512, 1024);
  transpose_w<<<dim3(32, 32), 256, 0, stream>>>(Wk, Wkt, 1024, 1024);
  transpose_w<<<dim3(32, 32), 256, 0, stream>>>(Wv, Wvt, 1024, 1024);
  transpose_w<<<dim3(32, 32), 256, 0, stream>>>(Wo, Wot, 1024, 1024);
  transpose_w<<<dim3(128, 32), 256, 0, stream>>>(W1, W1t, 1024, 4096);
  transpose_w<<<dim3(32, 128), 256, 0, stream>>>(W2, W2t, 4096, 1024);

  // layernorms
  ln_kernel<<<4608, 256, 0, stream>>>(grid_in, g_grid, b_grid, gn, 1024);
  ln_kernel<<<8192, 256, 0, stream>>>(qpos, g_q, b_q, qn, 512);

  // projections
  gemm128<0, 0, 0, 0, 1><<<dim3(36, 8), 256, 0, stream>>>(gn, Wkt, nullptr, Kb, nullptr, nullptr, 4608, 1024, 1024);
  gemm128<0, 0, 0, 0, 1><<<dim3(36, 8), 256, 0, stream>>>(gn, Wvt, nullptr, Vb, nullptr, nullptr, 4608, 1024, 1024);
  gemm128<0, 0, 0, 1, 1><<<dim3(64, 8), 256, 0, stream>>>(qn, Wqt, Qf, Qbf, nullptr, nullptr, 8192, 1024, 512);

  // attention
  attn_kernel<<<dim3(16, 16, 8), 256, 0, stream>>>(Qbf, Kb, Vb, atb);

  // x = Q + attn @ Wo
  gemm128<0, 0, 1, 1, 0><<<dim3(64, 8), 256, 0, stream>>>(atb, Wot, xf, nullptr, nullptr, Qf, 8192, 1024, 1024);

  // MLP
  ln_kernel<<<8192, 256, 0, stream>>>(xf, g_mlp, b_mlp, xnb, 1024);
  gemm128<1, 1, 0, 0, 1><<<dim3(64, 32), 256, 0, stream>>>(xnb, W1t, nullptr, hb, b1, nullptr, 8192, 4096, 1024);
  gemm128<1, 0, 1, 1, 0><<<dim3(64, 8), 256, 0, stream>>>(hb, W2t, (float*)d_out, nullptr, b2, xf, 8192, 1024, 4096);
}

// Round 2
// 407.827 us; speedup vs baseline: 1.7442x; 1.7442x over previous
//
#include <hip/hip_runtime.h>

// ---------------------------------------------------------------------------
// Types / helpers
// ---------------------------------------------------------------------------
typedef __bf16 bf16x8 __attribute__((ext_vector_type(8)));
typedef float  f32x4  __attribute__((ext_vector_type(4)));
typedef short  s16x8  __attribute__((ext_vector_type(8)));

__device__ __forceinline__ unsigned short f2b(float f) {
  unsigned int u = __float_as_uint(f);
  u += 0x7fffu + ((u >> 16) & 1u);           // round-to-nearest-even
  return (unsigned short)(u >> 16);
}
__device__ __forceinline__ float b2f(unsigned short h) {
  return __uint_as_float(((unsigned int)h) << 16);
}

__device__ __forceinline__ void gload_lds16(const unsigned short* g, unsigned short* l) {
  __builtin_amdgcn_global_load_lds((const __attribute__((address_space(1))) void*)g,
                                   (__attribute__((address_space(3))) void*)l, 16, 0, 0);
}

// ---------------------------------------------------------------------------
// Weight transpose: in (R x C) f32 row-major  ->  out (C x R) bf16 row-major
// ---------------------------------------------------------------------------
__global__ __launch_bounds__(256) void transpose_w(const float* __restrict__ in,
                                                   unsigned short* __restrict__ out,
                                                   int R, int C) {
  __shared__ float t[32][33];
  int c0 = blockIdx.x * 32, r0 = blockIdx.y * 32;
  int tx = threadIdx.x & 31, ty = threadIdx.x >> 5;  // 32 x 8
  for (int i = ty; i < 32; i += 8)
    t[i][tx] = in[(size_t)(r0 + i) * C + (c0 + tx)];
  __syncthreads();
  for (int i = ty; i < 32; i += 8)
    out[(size_t)(c0 + i) * R + (r0 + tx)] = f2b(t[tx][i]);
}

// ---------------------------------------------------------------------------
// V transpose: V (4608 x 1024) bf16 token-major -> Vt (8 x 1024 x 576) bf16
// Vt[(b*1024 + d)*576 + t] = V[(b*576 + t)*1024 + d]
// ---------------------------------------------------------------------------
__global__ __launch_bounds__(256) void transpose_v(const unsigned short* __restrict__ V,
                                                   unsigned short* __restrict__ Vt) {
  __shared__ unsigned short tile[64][72];
  const int t0 = blockIdx.x * 64;  // token tile (9)
  const int d0 = blockIdx.y * 64;  // d tile (16)
  const int b  = blockIdx.z;
  const int tid = threadIdx.x;
  const int r = tid >> 3, c8 = tid & 7;
#pragma unroll
  for (int p = 0; p < 2; ++p) {
    int row = p * 32 + r;  // token offset
    s16x8 v = *(const s16x8*)(V + ((size_t)(b * 576 + t0 + row) * 1024 + d0 + c8 * 8));
    *(s16x8*)&tile[row][c8 * 8] = v;
  }
  __syncthreads();
#pragma unroll
  for (int p = 0; p < 2; ++p) {
    int drow = p * 32 + r;  // d offset
    unsigned short tmp[8];
#pragma unroll
    for (int j = 0; j < 8; ++j) tmp[j] = tile[c8 * 8 + j][drow];
    *(s16x8*)(Vt + ((size_t)(b * 1024 + d0 + drow) * 576 + t0 + c8 * 8)) = *(const s16x8*)tmp;
  }
}

// ---------------------------------------------------------------------------
// LayerNorm over last dim (f32 in -> bf16 out). One block per row, 256 thr.
// ---------------------------------------------------------------------------
__global__ __launch_bounds__(256) void ln_kernel(const float* __restrict__ in,
                                                 const float* __restrict__ g,
                                                 const float* __restrict__ b,
                                                 unsigned short* __restrict__ out,
                                                 int cols) {
  int row = blockIdx.x;
  const float* x = in + (size_t)row * cols;
  float s = 0.f, s2 = 0.f;
  for (int c = threadIdx.x * 4; c < cols; c += 1024) {
    float4 v = *(const float4*)(x + c);
    s  += v.x + v.y + v.z + v.w;
    s2 += v.x * v.x + v.y * v.y + v.z * v.z + v.w * v.w;
  }
#pragma unroll
  for (int o = 32; o > 0; o >>= 1) { s += __shfl_down(s, o); s2 += __shfl_down(s2, o); }
  __shared__ float rs[4], rs2[4];
  int w = threadIdx.x >> 6;
  if ((threadIdx.x & 63) == 0) { rs[w] = s; rs2[w] = s2; }
  __syncthreads();
  s  = rs[0] + rs[1] + rs[2] + rs[3];
  s2 = rs2[0] + rs2[1] + rs2[2] + rs2[3];
  float inv  = 1.f / (float)cols;
  float mean = s * inv;
  float var  = s2 * inv - mean * mean;
  float rstd = rsqrtf(var + 1e-5f);
  unsigned short* outp = out + (size_t)row * cols;
  for (int c = threadIdx.x * 4; c < cols; c += 1024) {
    float4 v = *(const float4*)(x + c);
    ushort4 ov;
    ov.x = f2b((v.x - mean) * rstd * g[c + 0] + b[c + 0]);
    ov.y = f2b((v.y - mean) * rstd * g[c + 1] + b[c + 1]);
    ov.z = f2b((v.z - mean) * rstd * g[c + 2] + b[c + 2]);
    ov.w = f2b((v.w - mean) * rstd * g[c + 3] + b[c + 3]);
    *(ushort4*)(outp + c) = ov;
  }
}

// ---------------------------------------------------------------------------
// bf16 MFMA GEMM, 128x128 tile, BK=32, 4 waves (2x2 of 64x64 wave tiles).
// ---------------------------------------------------------------------------
template <int BIAS, int GELU, int RES, int WF32, int WBF16>
__global__ __launch_bounds__(256) void gemm128(const unsigned short* __restrict__ A,
                                               const unsigned short* __restrict__ Bt,
                                               float* __restrict__ Cf,
                                               unsigned short* __restrict__ Cb,
                                               const float* __restrict__ bias,
                                               const float* __restrict__ res,
                                               int M, int N, int K) {
  __shared__ unsigned short lA[2][128 * 32];
  __shared__ unsigned short lB[2][128 * 32];
  const int tid = threadIdx.x;
  const int w = tid >> 6, l = tid & 63;
  const int m0 = blockIdx.x * 128, n0 = blockIdx.y * 128;
  const int wm = w >> 1, wn = w & 1;
  const int srow = w * 32 + (l >> 2);
  const int scol = (l & 3) * 8;
  const size_t aBase = (size_t)(m0 + srow) * K + scol;
  const size_t bBase = (size_t)(n0 + srow) * K + scol;

  auto stage = [&](int kt, int buf) {
    const unsigned short* ga = A + aBase + (size_t)kt * 32;
    const unsigned short* gb = Bt + bBase + (size_t)kt * 32;
    unsigned short* la = &lA[buf][(w * 32) * 32];
    unsigned short* lb = &lB[buf][(w * 32) * 32];
    gload_lds16(ga, la);
    gload_lds16(ga + (size_t)16 * K, la + 16 * 32);
    gload_lds16(gb, lb);
    gload_lds16(gb + (size_t)16 * K, lb + 16 * 32);
  };

  f32x4 acc[4][4];
  f32x4 zz = {0.f, 0.f, 0.f, 0.f};
#pragma unroll
  for (int i = 0; i < 4; ++i)
#pragma unroll
    for (int j = 0; j < 4; ++j) acc[i][j] = zz;

  stage(0, 0);
  __syncthreads();
  const int KT = K >> 5;
  const int rl = l & 15, kb = l >> 4;
  for (int kt = 0; kt < KT; ++kt) {
    int buf = kt & 1;
    if (kt + 1 < KT) stage(kt + 1, buf ^ 1);
    bf16x8 af[4], bfr[4];
    const unsigned short* pA = lA[buf];
    const unsigned short* pB = lB[buf];
#pragma unroll
    for (int f = 0; f < 4; ++f) {
      af[f]  = *(const bf16x8*)(pA + (wm * 64 + f * 16 + rl) * 32 + kb * 8);
      bfr[f] = *(const bf16x8*)(pB + (wn * 64 + f * 16 + rl) * 32 + kb * 8);
    }
#pragma unroll
    for (int mf = 0; mf < 4; ++mf)
#pragma unroll
      for (int nf = 0; nf < 4; ++nf)
        acc[mf][nf] = __builtin_amdgcn_mfma_f32_16x16x32_bf16(af[mf], bfr[nf], acc[mf][nf], 0, 0, 0);
    __syncthreads();
  }

#pragma unroll
  for (int mf = 0; mf < 4; ++mf) {
#pragma unroll
    for (int nf = 0; nf < 4; ++nf) {
#pragma unroll
      for (int r = 0; r < 4; ++r) {
        int row = m0 + wm * 64 + mf * 16 + kb * 4 + r;
        int col = n0 + wn * 64 + nf * 16 + rl;
        float v = acc[mf][nf][r];
        if (BIAS) v += bias[col];
        if (GELU) {
          float t2 = 1.5957691f * (v + 0.044715f * v * v * v);  // 2*z
          float e = __expf(fminf(t2, 60.f));
          v = v * e / (e + 1.f);
        }
        if (RES) v += res[(size_t)row * N + col];
        if (WF32) Cf[(size_t)row * N + col] = v;
        if (WBF16) Cb[(size_t)row * N + col] = f2b(v);
      }
    }
  }
}

// ---------------------------------------------------------------------------
// MFMA flash attention. Block: 64 queries of one (b,h); 4 waves x 16 q-rows.
// Q: (8,1024,1024) bf16; K: (8,576,1024) bf16; Vt: (8,1024,576) bf16.
// All LDS tiles XOR-swizzled: 16B-granule g at row r holds global granule
// g^(r&7) (both-sides pattern: pre-swizzled global src + swizzled ds_read).
// ---------------------------------------------------------------------------
__global__ __launch_bounds__(256) void attn_mfma(const unsigned short* __restrict__ Qb,
                                                 const unsigned short* __restrict__ Kb,
                                                 const unsigned short* __restrict__ Vtb,
                                                 unsigned short* __restrict__ Ob) {
  __shared__ unsigned short Qs[64 * 64];
  __shared__ unsigned short Ks[2][64 * 64];
  __shared__ unsigned short Vs[2][64 * 64];
  __shared__ unsigned short Ps[64 * 64];

  const int t = threadIdx.x, w = t >> 6, l = t & 63;
  const int b = blockIdx.z, h = blockIdx.y, q0 = blockIdx.x * 64;
  const int rl = l & 15, kb = l >> 4;

  // stage a 64-row x 128B tile: LDS linear, global source pre-swizzled
  auto stage64 = [&](unsigned short* lds, const unsigned short* g, int gstride) {
#pragma unroll
    for (int p = 0; p < 2; ++p) {
      int row = p * 32 + w * 8 + (l >> 3);
      const unsigned short* src = g + (size_t)row * gstride + (((l & 7) ^ (row & 7)) * 8);
      gload_lds16(src, lds + p * 2048 + w * 512);
    }
  };

  const unsigned short* Qg = Qb + ((size_t)(b * 1024 + q0) * 1024 + h * 64);
  auto Kg = [&](int kt) { return Kb + ((size_t)(b * 576 + kt * 64) * 1024 + h * 64); };
  auto Vg = [&](int kt) { return Vtb + ((size_t)(b * 1024 + h * 64) * 576 + kt * 64); };

  stage64(Qs, Qg, 1024);
  stage64(Ks[0], Kg(0), 1024);
  stage64(Vs[0], Vg(0), 576);
  __syncthreads();

  // Q A-fragments for this wave's 16 rows (kept in regs for whole kernel)
  bf16x8 qf[2];
  {
    int row = w * 16 + rl;
#pragma unroll
    for (int kf = 0; kf < 2; ++kf)
      qf[kf] = *(const bf16x8*)(Qs + row * 64 + (((kf * 4 + kb) ^ (row & 7)) * 8));
  }

  float m_run[4], l_run[4];
  f32x4 accO[4];
#pragma unroll
  for (int r = 0; r < 4; ++r) { m_run[r] = -1e30f; l_run[r] = 0.f; }
  f32x4 zz = {0.f, 0.f, 0.f, 0.f};
#pragma unroll
  for (int nf = 0; nf < 4; ++nf) accO[nf] = zz;

  for (int kt = 0; kt < 9; ++kt) {
    const int buf = kt & 1;
    if (kt + 1 < 9) {
      stage64(Ks[buf ^ 1], Kg(kt + 1), 1024);
      stage64(Vs[buf ^ 1], Vg(kt + 1), 576);
    }

    // ---- S = Q K^T (16q x 64k per wave) ----
    f32x4 accS[4];
#pragma unroll
    for (int nf = 0; nf < 4; ++nf) accS[nf] = zz;
#pragma unroll
    for (int nf = 0; nf < 4; ++nf) {
      int row = nf * 16 + rl;
#pragma unroll
      for (int kf = 0; kf < 2; ++kf) {
        bf16x8 kfrag = *(const bf16x8*)(Ks[buf] + row * 64 + (((kf * 4 + kb) ^ (row & 7)) * 8));
        accS[nf] = __builtin_amdgcn_mfma_f32_16x16x32_bf16(qf[kf], kfrag, accS[nf], 0, 0, 0);
      }
    }

    // ---- online softmax (per lane: 4 q-rows x 4 key-cols) ----
    float sv[4][4];  // [nf][r]
#pragma unroll
    for (int nf = 0; nf < 4; ++nf)
#pragma unroll
      for (int r = 0; r < 4; ++r) sv[nf][r] = accS[nf][r] * 0.125f;

    float al[4];
#pragma unroll
    for (int r = 0; r < 4; ++r) {
      float mr = fmaxf(fmaxf(sv[0][r], sv[1][r]), fmaxf(sv[2][r], sv[3][r]));
#pragma unroll
      for (int xm = 1; xm < 16; xm <<= 1) mr = fmaxf(mr, __shfl_xor(mr, xm));
      float mn = fmaxf(m_run[r], mr);
      al[r] = __expf(m_run[r] - mn);
      m_run[r] = mn;
      float rs = 0.f;
#pragma unroll
      for (int nf = 0; nf < 4; ++nf) {
        sv[nf][r] = __expf(sv[nf][r] - mn);
        rs += sv[nf][r];
      }
#pragma unroll
      for (int xm = 1; xm < 16; xm <<= 1) rs += __shfl_xor(rs, xm);
      l_run[r] = l_run[r] * al[r] + rs;
    }

    // ---- P -> LDS (bf16, swizzled; wave-private rows) ----
#pragma unroll
    for (int nf = 0; nf < 4; ++nf)
#pragma unroll
      for (int r = 0; r < 4; ++r) {
        int q = w * 16 + kb * 4 + r;
        int col = nf * 16 + rl;
        Ps[q * 64 + (col ^ ((q & 7) << 3))] = f2b(sv[nf][r]);
      }

    // ---- rescale O ----
#pragma unroll
    for (int nf = 0; nf < 4; ++nf)
#pragma unroll
      for (int r = 0; r < 4; ++r) accO[nf][r] *= al[r];

    // intra-wave fence: P writes must land before P reads (wave-private block)
    asm volatile("s_waitcnt lgkmcnt(0)" ::: "memory");
    __builtin_amdgcn_sched_barrier(0);

    // ---- O += P V ----
    bf16x8 pf[2];
    {
      int row = w * 16 + rl;
#pragma unroll
      for (int kf = 0; kf < 2; ++kf)
        pf[kf] = *(const bf16x8*)(Ps + row * 64 + (((kf * 4 + kb) ^ (row & 7)) * 8));
    }
#pragma unroll
    for (int nf = 0; nf < 4; ++nf) {
      int row = nf * 16 + rl;
#pragma unroll
      for (int kf = 0; kf < 2; ++kf) {
        bf16x8 vfrag = *(const bf16x8*)(Vs[buf] + row * 64 + (((kf * 4 + kb) ^ (row & 7)) * 8));
        accO[nf] = __builtin_amdgcn_mfma_f32_16x16x32_bf16(pf[kf], vfrag, accO[nf], 0, 0, 0);
      }
    }

    __syncthreads();  // tile consumed; next iter may restage this buffer
  }

  // ---- epilogue: O /= l, write bf16 ----
#pragma unroll
  for (int nf = 0; nf < 4; ++nf) {
#pragma unroll
    for (int r = 0; r < 4; ++r) {
      float o = accO[nf][r] / l_run[r];
      size_t qg = (size_t)(b * 1024 + q0 + w * 16 + kb * 4 + r);
      Ob[qg * 1024 + h * 64 + nf * 16 + rl] = f2b(o);
    }
  }
}

// ---------------------------------------------------------------------------
// Launch
// ---------------------------------------------------------------------------
extern "C" void kernel_launch(void* const* d_in, const int* in_sizes, int n_in,
                              void* d_out, int out_size, void* d_ws, size_t ws_size,
                              hipStream_t stream) {
  const float* grid_in = (const float*)d_in[0];
  const float* qpos    = (const float*)d_in[1];
  const float* Wq      = (const float*)d_in[2];
  const float* Wk      = (const float*)d_in[3];
  const float* Wv      = (const float*)d_in[4];
  const float* Wo      = (const float*)d_in[5];
  const float* g_grid  = (const float*)d_in[6];
  const float* b_grid  = (const float*)d_in[7];
  const float* g_q     = (const float*)d_in[8];
  const float* b_q     = (const float*)d_in[9];
  const float* g_mlp   = (const float*)d_in[10];
  const float* b_mlp   = (const float*)d_in[11];
  const float* W1      = (const float*)d_in[12];
  const float* b1      = (const float*)d_in[13];
  const float* W2      = (const float*)d_in[14];
  const float* b2      = (const float*)d_in[15];

  char* ws = (char*)d_ws;
  size_t off = 0;
  auto alloc = [&](size_t bytes) -> void* {
    void* p = ws + off;
    off = (off + bytes + 255) & ~(size_t)255;
    return p;
  };

  unsigned short* Wqt = (unsigned short*)alloc((size_t)1024 * 512 * 2);
  unsigned short* Wkt = (unsigned short*)alloc((size_t)1024 * 1024 * 2);
  unsigned short* Wvt = (unsigned short*)alloc((size_t)1024 * 1024 * 2);
  unsigned short* Wot = (unsigned short*)alloc((size_t)1024 * 1024 * 2);
  unsigned short* W1t = (unsigned short*)alloc((size_t)4096 * 1024 * 2);
  unsigned short* W2t = (unsigned short*)alloc((size_t)1024 * 4096 * 2);
  unsigned short* gn  = (unsigned short*)alloc((size_t)4608 * 1024 * 2);
  unsigned short* qn  = (unsigned short*)alloc((size_t)8192 * 512 * 2);
  unsigned short* Kb  = (unsigned short*)alloc((size_t)4608 * 1024 * 2);
  unsigned short* Vb  = (unsigned short*)alloc((size_t)4608 * 1024 * 2);
  float*          Qf  = (float*)alloc((size_t)8192 * 1024 * 4);
  unsigned short* Qbf = (unsigned short*)alloc((size_t)8192 * 1024 * 2);
  unsigned short* atb = (unsigned short*)alloc((size_t)8192 * 1024 * 2);
  float*          xf  = (float*)alloc((size_t)8192 * 1024 * 4);
  unsigned short* xnb = (unsigned short*)alloc((size_t)8192 * 1024 * 2);
  unsigned short* hb  = (unsigned short*)alloc((size_t)8192 * 4096 * 2);
  // Vt aliases hb: Vt is dead before the W1 GEMM writes hb (stream-ordered)
  unsigned short* Vtb = hb;
  (void)ws_size; (void)in_sizes; (void)n_in; (void)out_size;

  // weight transposes (f32 -> bf16, N-major)
  transpose_w<<<dim3(32, 16), 256, 0, stream>>>(Wq, Wqt, 512, 1024);
  transpose_w<<<dim3(32, 32), 256, 0, stream>>>(Wk, Wkt, 1024, 1024);
  transpose_w<<<dim3(32, 32), 256, 0, stream>>>(Wv, Wvt, 1024, 1024);
  transpose_w<<<dim3(32, 32), 256, 0, stream>>>(Wo, Wot, 1024, 1024);
  transpose_w<<<dim3(128, 32), 256, 0, stream>>>(W1, W1t, 1024, 4096);
  transpose_w<<<dim3(32, 128), 256, 0, stream>>>(W2, W2t, 4096, 1024);

  // layernorms
  ln_kernel<<<4608, 256, 0, stream>>>(grid_in, g_grid, b_grid, gn, 1024);
  ln_kernel<<<8192, 256, 0, stream>>>(qpos, g_q, b_q, qn, 512);

  // projections
  gemm128<0, 0, 0, 0, 1><<<dim3(36, 8), 256, 0, stream>>>(gn, Wkt, nullptr, Kb, nullptr, nullptr, 4608, 1024, 1024);
  gemm128<0, 0, 0, 0, 1><<<dim3(36, 8), 256, 0, stream>>>(gn, Wvt, nullptr, Vb, nullptr, nullptr, 4608, 1024, 1024);
  gemm128<0, 0, 0, 1, 1><<<dim3(64, 8), 256, 0, stream>>>(qn, Wqt, Qf, Qbf, nullptr, nullptr, 8192, 1024, 512);

  // V transpose for PV B-operand
  transpose_v<<<dim3(9, 16, 8), 256, 0, stream>>>(Vb, Vtb);

  // attention (MFMA)
  attn_mfma<<<dim3(16, 16, 8), 256, 0, stream>>>(Qbf, Kb, Vtb, atb);

  // x = Q + attn @ Wo
  gemm128<0, 0, 1, 1, 0><<<dim3(64, 8), 256, 0, stream>>>(atb, Wot, xf, nullptr, nullptr, Qf, 8192, 1024, 1024);

  // MLP
  ln_kernel<<<8192, 256, 0, stream>>>(xf, g_mlp, b_mlp, xnb, 1024);
  gemm128<1, 1, 0, 0, 1><<<dim3(64, 32), 256, 0, stream>>>(xnb, W1t, nullptr, hb, b1, nullptr, 8192, 4096, 1024);
  gemm128<1, 0, 1, 1, 0><<<dim3(64, 8), 256, 0, stream>>>(hb, W2t, (float*)d_out, nullptr, b2, xf, 8192, 1024, 4096);
}

// Round 3
// 378.298 us; speedup vs baseline: 1.8804x; 1.0781x over previous
//
#include <hip/hip_runtime.h>

// ---------------------------------------------------------------------------
// Types / helpers
// ---------------------------------------------------------------------------
typedef __bf16 bf16x8 __attribute__((ext_vector_type(8)));
typedef float  f32x4  __attribute__((ext_vector_type(4)));
typedef short  s16x8  __attribute__((ext_vector_type(8)));

__device__ __forceinline__ unsigned short f2b(float f) {
  unsigned int u = __float_as_uint(f);
  u += 0x7fffu + ((u >> 16) & 1u);           // round-to-nearest-even
  return (unsigned short)(u >> 16);
}
__device__ __forceinline__ float b2f(unsigned short h) {
  return __uint_as_float(((unsigned int)h) << 16);
}

__device__ __forceinline__ void gload_lds16(const unsigned short* g, unsigned short* l) {
  __builtin_amdgcn_global_load_lds((const __attribute__((address_space(1))) void*)g,
                                   (__attribute__((address_space(3))) void*)l, 16, 0, 0);
}

__device__ __forceinline__ void bar() {
  __builtin_amdgcn_sched_barrier(0);
  asm volatile("" ::: "memory");
  __builtin_amdgcn_s_barrier();
  asm volatile("" ::: "memory");
  __builtin_amdgcn_sched_barrier(0);
}

#define WAIT_LGKM0 do { asm volatile("s_waitcnt lgkmcnt(0)" ::: "memory"); \
                        __builtin_amdgcn_sched_barrier(0); } while (0)

// ---------------------------------------------------------------------------
// Weight transpose: in (R x C) f32 row-major  ->  out (C x R) bf16 row-major
// ---------------------------------------------------------------------------
__global__ __launch_bounds__(256) void transpose_w(const float* __restrict__ in,
                                                   unsigned short* __restrict__ out,
                                                   int R, int C) {
  __shared__ float t[32][33];
  int c0 = blockIdx.x * 32, r0 = blockIdx.y * 32;
  int tx = threadIdx.x & 31, ty = threadIdx.x >> 5;  // 32 x 8
  for (int i = ty; i < 32; i += 8)
    t[i][tx] = in[(size_t)(r0 + i) * C + (c0 + tx)];
  __syncthreads();
  for (int i = ty; i < 32; i += 8)
    out[(size_t)(c0 + i) * R + (r0 + tx)] = f2b(t[tx][i]);
}

// ---------------------------------------------------------------------------
// V transpose: V (4608 x 1024) bf16 token-major -> Vt (8 x 1024 x 576) bf16
// ---------------------------------------------------------------------------
__global__ __launch_bounds__(256) void transpose_v(const unsigned short* __restrict__ V,
                                                   unsigned short* __restrict__ Vt) {
  __shared__ unsigned short tile[64][72];
  const int t0 = blockIdx.x * 64;
  const int d0 = blockIdx.y * 64;
  const int b  = blockIdx.z;
  const int tid = threadIdx.x;
  const int r = tid >> 3, c8 = tid & 7;
#pragma unroll
  for (int p = 0; p < 2; ++p) {
    int row = p * 32 + r;
    s16x8 v = *(const s16x8*)(V + ((size_t)(b * 576 + t0 + row) * 1024 + d0 + c8 * 8));
    *(s16x8*)&tile[row][c8 * 8] = v;
  }
  __syncthreads();
#pragma unroll
  for (int p = 0; p < 2; ++p) {
    int drow = p * 32 + r;
    unsigned short tmp[8];
#pragma unroll
    for (int j = 0; j < 8; ++j) tmp[j] = tile[c8 * 8 + j][drow];
    *(s16x8*)(Vt + ((size_t)(b * 1024 + d0 + drow) * 576 + t0 + c8 * 8)) = *(const s16x8*)tmp;
  }
}

// ---------------------------------------------------------------------------
// LayerNorm over last dim (f32 in -> bf16 out). One block per row, 256 thr.
// ---------------------------------------------------------------------------
__global__ __launch_bounds__(256) void ln_kernel(const float* __restrict__ in,
                                                 const float* __restrict__ g,
                                                 const float* __restrict__ b,
                                                 unsigned short* __restrict__ out,
                                                 int cols) {
  int row = blockIdx.x;
  const float* x = in + (size_t)row * cols;
  float s = 0.f, s2 = 0.f;
  for (int c = threadIdx.x * 4; c < cols; c += 1024) {
    float4 v = *(const float4*)(x + c);
    s  += v.x + v.y + v.z + v.w;
    s2 += v.x * v.x + v.y * v.y + v.z * v.z + v.w * v.w;
  }
#pragma unroll
  for (int o = 32; o > 0; o >>= 1) { s += __shfl_down(s, o); s2 += __shfl_down(s2, o); }
  __shared__ float rs[4], rs2[4];
  int w = threadIdx.x >> 6;
  if ((threadIdx.x & 63) == 0) { rs[w] = s; rs2[w] = s2; }
  __syncthreads();
  s  = rs[0] + rs[1] + rs[2] + rs[3];
  s2 = rs2[0] + rs2[1] + rs2[2] + rs2[3];
  float inv  = 1.f / (float)cols;
  float mean = s * inv;
  float var  = s2 * inv - mean * mean;
  float rstd = rsqrtf(var + 1e-5f);
  unsigned short* outp = out + (size_t)row * cols;
  for (int c = threadIdx.x * 4; c < cols; c += 1024) {
    float4 v = *(const float4*)(x + c);
    ushort4 ov;
    ov.x = f2b((v.x - mean) * rstd * g[c + 0] + b[c + 0]);
    ov.y = f2b((v.y - mean) * rstd * g[c + 1] + b[c + 1]);
    ov.z = f2b((v.z - mean) * rstd * g[c + 2] + b[c + 2]);
    ov.w = f2b((v.w - mean) * rstd * g[c + 3] + b[c + 3]);
    *(ushort4*)(outp + c) = ov;
  }
}

// ---------------------------------------------------------------------------
// 8-phase counted-vmcnt MFMA GEMM (T2+T3+T4+T5).  Tile BM x 256, BK=64,
// 8 waves (2M x 4N), per-wave output (BM/2) x 64.
// A: (M x K) bf16 row-major.  Bt: (N x K) bf16 row-major.
// Half-tile ring, issue order per tile [B0,B1,A0,A1]; during tile t's 4
// phases we issue (t+1).A1 , (t+2).B0 , (t+2).B1 , (t+2).A0.  Gate before
// tile t: vmcnt(4+LA) -> tile t fully landed, 3 halves in flight.
// ds_reads front-loaded (p1: all B + lower A; p3: upper A) so every LDS
// region's reads complete (lgkmcnt(0) + barrier) before its overwrite issues.
// LDS XOR-swizzle via pre-swizzled global source + linear gload_lds dest.
// ---------------------------------------------------------------------------
template <int BM, int BIAS, int GELU, int RES, int WF32, int WBF16>
__global__ __launch_bounds__(512) void gemm256(const unsigned short* __restrict__ A,
                                               const unsigned short* __restrict__ Bt,
                                               float* __restrict__ Cf,
                                               unsigned short* __restrict__ Cb,
                                               const float* __restrict__ bias,
                                               const float* __restrict__ res,
                                               int M, int N, int K) {
  constexpr int MF = BM / 32;   // per-wave M frags (8 or 4)
  constexpr int MH = MF / 2;
  constexpr int LA = BM / 128;  // gload_lds per wave per A-half (2 or 1)
  __shared__ unsigned short L[2][(BM + 256) * 64];
  const int tid = threadIdx.x;
  const int w = tid >> 6, l = tid & 63;
  const int rl = l & 15, kb = l >> 4;
  const int wm = w >> 2, wn = w & 3;
  const int m0 = blockIdx.x * BM, n0 = blockIdx.y * 256;
  const int NT = K >> 6;
  const int colsw = ((l & 7) ^ (l >> 3)) * 8;  // pre-swizzled source granule
  const int lrow = l >> 3;

  // half: 0=B0(rows n0..+128), 1=B1, 2=A0(rows m0..+BM/2), 3=A1
  auto stage = [&](int t, int half) {
    if (t >= NT) return;
    unsigned short* base = L[t & 1];
    if (half < 2) {
      const unsigned short* g = Bt + (size_t)(n0 + half * 128) * K + t * 64;
#pragma unroll
      for (int j = 0; j < 2; ++j) {
        int row = w * 16 + j * 8;
        gload_lds16(g + (size_t)(row + lrow) * K + colsw,
                    base + BM * 64 + half * 8192 + row * 64);
      }
    } else {
      const int h = half - 2;
      const unsigned short* g = A + (size_t)(m0 + h * (BM / 2)) * K + t * 64;
#pragma unroll
      for (int j = 0; j < LA; ++j) {
        int row = w * (8 * LA) + j * 8;
        gload_lds16(g + (size_t)(row + lrow) * K + colsw,
                    base + h * (BM / 2) * 64 + row * 64);
      }
    }
  };

  f32x4 acc[MF][4];
  f32x4 zz = {0.f, 0.f, 0.f, 0.f};
#pragma unroll
  for (int i = 0; i < MF; ++i)
#pragma unroll
    for (int j = 0; j < 4; ++j) acc[i][j] = zz;

  // prologue: tile0 all 4 halves, tile1 first 3
  stage(0, 0); stage(0, 1); stage(0, 2); stage(0, 3);
  stage(1, 0); stage(1, 1); stage(1, 2);

  const int aoff = wm * (BM / 2) * 64;
  const int boff = BM * 64 + (wn >> 1) * 8192 + (wn & 1) * 64 * 64;

  for (int t = 0; t < NT; ++t) {
    const unsigned short* Lb = L[t & 1];
    // ---- gate: tile t fully landed; 3 halves (t+1/t+2) in flight ----
    if (t + 1 < NT) {
      if constexpr (LA == 2) asm volatile("s_waitcnt vmcnt(6)" ::: "memory");
      else                   asm volatile("s_waitcnt vmcnt(5)" ::: "memory");
    } else {
      asm volatile("s_waitcnt vmcnt(0)" ::: "memory");
    }
    __builtin_amdgcn_sched_barrier(0);
    bar();

    bf16x8 af[MH][2], bf[4][2];
    // ---- p1: read all B + lower A; stage (t+1).A1; MFMA q0 ----
#pragma unroll
    for (int mf = 0; mf < MH; ++mf)
#pragma unroll
      for (int kf = 0; kf < 2; ++kf)
        af[mf][kf] = *(const bf16x8*)(Lb + aoff + (mf * 16 + rl) * 64 +
                                      (((kf * 4 + kb) ^ (rl & 7)) * 8));
#pragma unroll
    for (int nf = 0; nf < 4; ++nf)
#pragma unroll
      for (int kf = 0; kf < 2; ++kf)
        bf[nf][kf] = *(const bf16x8*)(Lb + boff + (nf * 16 + rl) * 64 +
                                      (((kf * 4 + kb) ^ (rl & 7)) * 8));
    stage(t + 1, 3);
    WAIT_LGKM0;
    __builtin_amdgcn_s_setprio(1);
#pragma unroll
    for (int mf = 0; mf < MH; ++mf)
#pragma unroll
      for (int nf = 0; nf < 2; ++nf)
#pragma unroll
        for (int kf = 0; kf < 2; ++kf)
          acc[mf][nf] = __builtin_amdgcn_mfma_f32_16x16x32_bf16(af[mf][kf], bf[nf][kf], acc[mf][nf], 0, 0, 0);
    __builtin_amdgcn_s_setprio(0);
    bar();

    // ---- p2: stage (t+2).B0; MFMA q1 ----
    stage(t + 2, 0);
    __builtin_amdgcn_s_setprio(1);
#pragma unroll
    for (int mf = 0; mf < MH; ++mf)
#pragma unroll
      for (int nf = 2; nf < 4; ++nf)
#pragma unroll
        for (int kf = 0; kf < 2; ++kf)
          acc[mf][nf] = __builtin_amdgcn_mfma_f32_16x16x32_bf16(af[mf][kf], bf[nf][kf], acc[mf][nf], 0, 0, 0);
    __builtin_amdgcn_s_setprio(0);
    bar();

    // ---- p3: read upper A; stage (t+2).B1; MFMA q2 ----
#pragma unroll
    for (int mf = 0; mf < MH; ++mf)
#pragma unroll
      for (int kf = 0; kf < 2; ++kf)
        af[mf][kf] = *(const bf16x8*)(Lb + aoff + ((MH + mf) * 16 + rl) * 64 +
                                      (((kf * 4 + kb) ^ (rl & 7)) * 8));
    stage(t + 2, 1);
    WAIT_LGKM0;
    __builtin_amdgcn_s_setprio(1);
#pragma unroll
    for (int mf = 0; mf < MH; ++mf)
#pragma unroll
      for (int nf = 0; nf < 2; ++nf)
#pragma unroll
        for (int kf = 0; kf < 2; ++kf)
          acc[MH + mf][nf] = __builtin_amdgcn_mfma_f32_16x16x32_bf16(af[mf][kf], bf[nf][kf], acc[MH + mf][nf], 0, 0, 0);
    __builtin_amdgcn_s_setprio(0);
    bar();

    // ---- p4: stage (t+2).A0; MFMA q3 ----  (next gate's bar closes phase)
    stage(t + 2, 2);
    __builtin_amdgcn_s_setprio(1);
#pragma unroll
    for (int mf = 0; mf < MH; ++mf)
#pragma unroll
      for (int nf = 2; nf < 4; ++nf)
#pragma unroll
        for (int kf = 0; kf < 2; ++kf)
          acc[MH + mf][nf] = __builtin_amdgcn_mfma_f32_16x16x32_bf16(af[mf][kf], bf[nf][kf], acc[MH + mf][nf], 0, 0, 0);
    __builtin_amdgcn_s_setprio(0);
  }

  // ---- epilogue ----
#pragma unroll
  for (int mf = 0; mf < MF; ++mf) {
#pragma unroll
    for (int nf = 0; nf < 4; ++nf) {
#pragma unroll
      for (int r = 0; r < 4; ++r) {
        int row = m0 + wm * (BM / 2) + mf * 16 + kb * 4 + r;
        int col = n0 + wn * 64 + nf * 16 + rl;
        float v = acc[mf][nf][r];
        if (BIAS) v += bias[col];
        if (GELU) {
          float t2 = 1.5957691f * (v + 0.044715f * v * v * v);  // 2*z
          float e = __expf(fminf(t2, 60.f));
          v = v * e / (e + 1.f);
        }
        if (RES) v += res[(size_t)row * N + col];
        if (WF32) Cf[(size_t)row * N + col] = v;
        if (WBF16) Cb[(size_t)row * N + col] = f2b(v);
      }
    }
  }
}

// ---------------------------------------------------------------------------
// MFMA flash attention (unchanged from round 2).
// ---------------------------------------------------------------------------
__global__ __launch_bounds__(256) void attn_mfma(const unsigned short* __restrict__ Qb,
                                                 const unsigned short* __restrict__ Kb,
                                                 const unsigned short* __restrict__ Vtb,
                                                 unsigned short* __restrict__ Ob) {
  __shared__ unsigned short Qs[64 * 64];
  __shared__ unsigned short Ks[2][64 * 64];
  __shared__ unsigned short Vs[2][64 * 64];
  __shared__ unsigned short Ps[64 * 64];

  const int t = threadIdx.x, w = t >> 6, l = t & 63;
  const int b = blockIdx.z, h = blockIdx.y, q0 = blockIdx.x * 64;
  const int rl = l & 15, kb = l >> 4;

  auto stage64 = [&](unsigned short* lds, const unsigned short* g, int gstride) {
#pragma unroll
    for (int p = 0; p < 2; ++p) {
      int row = p * 32 + w * 8 + (l >> 3);
      const unsigned short* src = g + (size_t)row * gstride + (((l & 7) ^ (row & 7)) * 8);
      gload_lds16(src, lds + p * 2048 + w * 512);
    }
  };

  const unsigned short* Qg = Qb + ((size_t)(b * 1024 + q0) * 1024 + h * 64);
  auto Kg = [&](int kt) { return Kb + ((size_t)(b * 576 + kt * 64) * 1024 + h * 64); };
  auto Vg = [&](int kt) { return Vtb + ((size_t)(b * 1024 + h * 64) * 576 + kt * 64); };

  stage64(Qs, Qg, 1024);
  stage64(Ks[0], Kg(0), 1024);
  stage64(Vs[0], Vg(0), 576);
  __syncthreads();

  bf16x8 qf[2];
  {
    int row = w * 16 + rl;
#pragma unroll
    for (int kf = 0; kf < 2; ++kf)
      qf[kf] = *(const bf16x8*)(Qs + row * 64 + (((kf * 4 + kb) ^ (row & 7)) * 8));
  }

  float m_run[4], l_run[4];
  f32x4 accO[4];
#pragma unroll
  for (int r = 0; r < 4; ++r) { m_run[r] = -1e30f; l_run[r] = 0.f; }
  f32x4 zz = {0.f, 0.f, 0.f, 0.f};
#pragma unroll
  for (int nf = 0; nf < 4; ++nf) accO[nf] = zz;

  for (int kt = 0; kt < 9; ++kt) {
    const int buf = kt & 1;
    if (kt + 1 < 9) {
      stage64(Ks[buf ^ 1], Kg(kt + 1), 1024);
      stage64(Vs[buf ^ 1], Vg(kt + 1), 576);
    }

    f32x4 accS[4];
#pragma unroll
    for (int nf = 0; nf < 4; ++nf) accS[nf] = zz;
#pragma unroll
    for (int nf = 0; nf < 4; ++nf) {
      int row = nf * 16 + rl;
#pragma unroll
      for (int kf = 0; kf < 2; ++kf) {
        bf16x8 kfrag = *(const bf16x8*)(Ks[buf] + row * 64 + (((kf * 4 + kb) ^ (row & 7)) * 8));
        accS[nf] = __builtin_amdgcn_mfma_f32_16x16x32_bf16(qf[kf], kfrag, accS[nf], 0, 0, 0);
      }
    }

    float sv[4][4];
#pragma unroll
    for (int nf = 0; nf < 4; ++nf)
#pragma unroll
      for (int r = 0; r < 4; ++r) sv[nf][r] = accS[nf][r] * 0.125f;

    float al[4];
#pragma unroll
    for (int r = 0; r < 4; ++r) {
      float mr = fmaxf(fmaxf(sv[0][r], sv[1][r]), fmaxf(sv[2][r], sv[3][r]));
#pragma unroll
      for (int xm = 1; xm < 16; xm <<= 1) mr = fmaxf(mr, __shfl_xor(mr, xm));
      float mn = fmaxf(m_run[r], mr);
      al[r] = __expf(m_run[r] - mn);
      m_run[r] = mn;
      float rs = 0.f;
#pragma unroll
      for (int nf = 0; nf < 4; ++nf) {
        sv[nf][r] = __expf(sv[nf][r] - mn);
        rs += sv[nf][r];
      }
#pragma unroll
      for (int xm = 1; xm < 16; xm <<= 1) rs += __shfl_xor(rs, xm);
      l_run[r] = l_run[r] * al[r] + rs;
    }

#pragma unroll
    for (int nf = 0; nf < 4; ++nf)
#pragma unroll
      for (int r = 0; r < 4; ++r) {
        int q = w * 16 + kb * 4 + r;
        int col = nf * 16 + rl;
        Ps[q * 64 + (col ^ ((q & 7) << 3))] = f2b(sv[nf][r]);
      }

#pragma unroll
    for (int nf = 0; nf < 4; ++nf)
#pragma unroll
      for (int r = 0; r < 4; ++r) accO[nf][r] *= al[r];

    asm volatile("s_waitcnt lgkmcnt(0)" ::: "memory");
    __builtin_amdgcn_sched_barrier(0);

    bf16x8 pf[2];
    {
      int row = w * 16 + rl;
#pragma unroll
      for (int kf = 0; kf < 2; ++kf)
        pf[kf] = *(const bf16x8*)(Ps + row * 64 + (((kf * 4 + kb) ^ (row & 7)) * 8));
    }
#pragma unroll
    for (int nf = 0; nf < 4; ++nf) {
      int row = nf * 16 + rl;
#pragma unroll
      for (int kf = 0; kf < 2; ++kf) {
        bf16x8 vfrag = *(const bf16x8*)(Vs[buf] + row * 64 + (((kf * 4 + kb) ^ (row & 7)) * 8));
        accO[nf] = __builtin_amdgcn_mfma_f32_16x16x32_bf16(pf[kf], vfrag, accO[nf], 0, 0, 0);
      }
    }

    __syncthreads();
  }

#pragma unroll
  for (int nf = 0; nf < 4; ++nf) {
#pragma unroll
    for (int r = 0; r < 4; ++r) {
      float o = accO[nf][r] / l_run[r];
      size_t qg = (size_t)(b * 1024 + q0 + w * 16 + kb * 4 + r);
      Ob[qg * 1024 + h * 64 + nf * 16 + rl] = f2b(o);
    }
  }
}

// ---------------------------------------------------------------------------
// Launch
// ---------------------------------------------------------------------------
extern "C" void kernel_launch(void* const* d_in, const int* in_sizes, int n_in,
                              void* d_out, int out_size, void* d_ws, size_t ws_size,
                              hipStream_t stream) {
  const float* grid_in = (const float*)d_in[0];
  const float* qpos    = (const float*)d_in[1];
  const float* Wq      = (const float*)d_in[2];
  const float* Wk      = (const float*)d_in[3];
  const float* Wv      = (const float*)d_in[4];
  const float* Wo      = (const float*)d_in[5];
  const float* g_grid  = (const float*)d_in[6];
  const float* b_grid  = (const float*)d_in[7];
  const float* g_q     = (const float*)d_in[8];
  const float* b_q     = (const float*)d_in[9];
  const float* g_mlp   = (const float*)d_in[10];
  const float* b_mlp   = (const float*)d_in[11];
  const float* W1      = (const float*)d_in[12];
  const float* b1      = (const float*)d_in[13];
  const float* W2      = (const float*)d_in[14];
  const float* b2      = (const float*)d_in[15];

  char* ws = (char*)d_ws;
  size_t off = 0;
  auto alloc = [&](size_t bytes) -> void* {
    void* p = ws + off;
    off = (off + bytes + 255) & ~(size_t)255;
    return p;
  };

  unsigned short* Wqt = (unsigned short*)alloc((size_t)1024 * 512 * 2);
  unsigned short* Wkt = (unsigned short*)alloc((size_t)1024 * 1024 * 2);
  unsigned short* Wvt = (unsigned short*)alloc((size_t)1024 * 1024 * 2);
  unsigned short* Wot = (unsigned short*)alloc((size_t)1024 * 1024 * 2);
  unsigned short* W1t = (unsigned short*)alloc((size_t)4096 * 1024 * 2);
  unsigned short* W2t = (unsigned short*)alloc((size_t)1024 * 4096 * 2);
  unsigned short* gn  = (unsigned short*)alloc((size_t)4608 * 1024 * 2);
  unsigned short* qn  = (unsigned short*)alloc((size_t)8192 * 512 * 2);
  unsigned short* Kb  = (unsigned short*)alloc((size_t)4608 * 1024 * 2);
  unsigned short* Vb  = (unsigned short*)alloc((size_t)4608 * 1024 * 2);
  float*          Qf  = (float*)alloc((size_t)8192 * 1024 * 4);
  unsigned short* Qbf = (unsigned short*)alloc((size_t)8192 * 1024 * 2);
  unsigned short* atb = (unsigned short*)alloc((size_t)8192 * 1024 * 2);
  float*          xf  = (float*)alloc((size_t)8192 * 1024 * 4);
  unsigned short* xnb = (unsigned short*)alloc((size_t)8192 * 1024 * 2);
  unsigned short* hb  = (unsigned short*)alloc((size_t)8192 * 4096 * 2);
  unsigned short* Vtb = hb;  // dead before W1 GEMM writes hb (stream-ordered)
  (void)ws_size; (void)in_sizes; (void)n_in; (void)out_size;

  // weight transposes (f32 -> bf16, N-major)
  transpose_w<<<dim3(32, 16), 256, 0, stream>>>(Wq, Wqt, 512, 1024);
  transpose_w<<<dim3(32, 32), 256, 0, stream>>>(Wk, Wkt, 1024, 1024);
  transpose_w<<<dim3(32, 32), 256, 0, stream>>>(Wv, Wvt, 1024, 1024);
  transpose_w<<<dim3(32, 32), 256, 0, stream>>>(Wo, Wot, 1024, 1024);
  transpose_w<<<dim3(128, 32), 256, 0, stream>>>(W1, W1t, 1024, 4096);
  transpose_w<<<dim3(32, 128), 256, 0, stream>>>(W2, W2t, 4096, 1024);

  // layernorms
  ln_kernel<<<4608, 256, 0, stream>>>(grid_in, g_grid, b_grid, gn, 1024);
  ln_kernel<<<8192, 256, 0, stream>>>(qpos, g_q, b_q, qn, 512);

  // projections (8-phase GEMM)
  gemm256<128, 0, 0, 0, 0, 1><<<dim3(36, 4), 512, 0, stream>>>(gn, Wkt, nullptr, Kb, nullptr, nullptr, 4608, 1024, 1024);
  gemm256<128, 0, 0, 0, 0, 1><<<dim3(36, 4), 512, 0, stream>>>(gn, Wvt, nullptr, Vb, nullptr, nullptr, 4608, 1024, 1024);
  gemm256<128, 0, 0, 0, 1, 1><<<dim3(64, 4), 512, 0, stream>>>(qn, Wqt, Qf, Qbf, nullptr, nullptr, 8192, 1024, 512);

  // V transpose for PV B-operand
  transpose_v<<<dim3(9, 16, 8), 256, 0, stream>>>(Vb, Vtb);

  // attention (MFMA)
  attn_mfma<<<dim3(16, 16, 8), 256, 0, stream>>>(Qbf, Kb, Vtb, atb);

  // x = Q + attn @ Wo
  gemm256<128, 0, 0, 1, 1, 0><<<dim3(64, 4), 512, 0, stream>>>(atb, Wot, xf, nullptr, nullptr, Qf, 8192, 1024, 1024);

  // MLP
  ln_kernel<<<8192, 256, 0, stream>>>(xf, g_mlp, b_mlp, xnb, 1024);
  gemm256<256, 1, 1, 0, 0, 1><<<dim3(32, 16), 512, 0, stream>>>(xnb, W1t, nullptr, hb, b1, nullptr, 8192, 4096, 1024);
  gemm256<128, 1, 0, 1, 1, 0><<<dim3(64, 4), 512, 0, stream>>>(hb, W2t, (float*)d_out, nullptr, b2, xf, 8192, 1024, 4096);
}

// Round 4
// 368.597 us; speedup vs baseline: 1.9299x; 1.0263x over previous
//
#include <hip/hip_runtime.h>

// ---------------------------------------------------------------------------
// Types / helpers
// ---------------------------------------------------------------------------
typedef __bf16 bf16x8 __attribute__((ext_vector_type(8)));
typedef float  f32x4  __attribute__((ext_vector_type(4)));
typedef short  s16x8  __attribute__((ext_vector_type(8)));

__device__ __forceinline__ unsigned short f2b(float f) {
  unsigned int u = __float_as_uint(f);
  u += 0x7fffu + ((u >> 16) & 1u);           // round-to-nearest-even
  return (unsigned short)(u >> 16);
}
__device__ __forceinline__ float b2f(unsigned short h) {
  return __uint_as_float(((unsigned int)h) << 16);
}

__device__ __forceinline__ void gload_lds16(const unsigned short* g, unsigned short* l) {
  __builtin_amdgcn_global_load_lds((const __attribute__((address_space(1))) void*)g,
                                   (__attribute__((address_space(3))) void*)l, 16, 0, 0);
}

__device__ __forceinline__ void bar() {
  __builtin_amdgcn_sched_barrier(0);
  asm volatile("" ::: "memory");
  __builtin_amdgcn_s_barrier();
  asm volatile("" ::: "memory");
  __builtin_amdgcn_sched_barrier(0);
}

#define WAIT_LGKM0 do { asm volatile("s_waitcnt lgkmcnt(0)" ::: "memory"); \
                        __builtin_amdgcn_sched_barrier(0); } while (0)

// ---------------------------------------------------------------------------
// Weight transpose: in (R x C) f32 row-major  ->  out (C x R) bf16 row-major
// ---------------------------------------------------------------------------
__global__ __launch_bounds__(256) void transpose_w(const float* __restrict__ in,
                                                   unsigned short* __restrict__ out,
                                                   int R, int C) {
  __shared__ float t[32][33];
  int c0 = blockIdx.x * 32, r0 = blockIdx.y * 32;
  int tx = threadIdx.x & 31, ty = threadIdx.x >> 5;  // 32 x 8
  for (int i = ty; i < 32; i += 8)
    t[i][tx] = in[(size_t)(r0 + i) * C + (c0 + tx)];
  __syncthreads();
  for (int i = ty; i < 32; i += 8)
    out[(size_t)(c0 + i) * R + (r0 + tx)] = f2b(t[tx][i]);
}

// ---------------------------------------------------------------------------
// V transpose: V rows (4608 x vstride, d at cols 0..1023) -> Vt (8,1024,576)
// Vt[(b*1024 + d)*576 + t] = V[(b*576 + t)*vstride + d]
// ---------------------------------------------------------------------------
__global__ __launch_bounds__(256) void transpose_v(const unsigned short* __restrict__ V,
                                                   unsigned short* __restrict__ Vt,
                                                   int vstride) {
  __shared__ unsigned short tile[64][72];
  const int t0 = blockIdx.x * 64;
  const int d0 = blockIdx.y * 64;
  const int b  = blockIdx.z;
  const int tid = threadIdx.x;
  const int r = tid >> 3, c8 = tid & 7;
#pragma unroll
  for (int p = 0; p < 2; ++p) {
    int row = p * 32 + r;
    s16x8 v = *(const s16x8*)(V + ((size_t)(b * 576 + t0 + row) * vstride + d0 + c8 * 8));
    *(s16x8*)&tile[row][c8 * 8] = v;
  }
  __syncthreads();
#pragma unroll
  for (int p = 0; p < 2; ++p) {
    int drow = p * 32 + r;
    unsigned short tmp[8];
#pragma unroll
    for (int j = 0; j < 8; ++j) tmp[j] = tile[c8 * 8 + j][drow];
    *(s16x8*)(Vt + ((size_t)(b * 1024 + d0 + drow) * 576 + t0 + c8 * 8)) = *(const s16x8*)tmp;
  }
}

// ---------------------------------------------------------------------------
// LayerNorm over last dim (f32 in -> bf16 out). One block per row, 256 thr.
// ---------------------------------------------------------------------------
__global__ __launch_bounds__(256) void ln_kernel(const float* __restrict__ in,
                                                 const float* __restrict__ g,
                                                 const float* __restrict__ b,
                                                 unsigned short* __restrict__ out,
                                                 int cols) {
  int row = blockIdx.x;
  const float* x = in + (size_t)row * cols;
  float s = 0.f, s2 = 0.f;
  for (int c = threadIdx.x * 4; c < cols; c += 1024) {
    float4 v = *(const float4*)(x + c);
    s  += v.x + v.y + v.z + v.w;
    s2 += v.x * v.x + v.y * v.y + v.z * v.z + v.w * v.w;
  }
#pragma unroll
  for (int o = 32; o > 0; o >>= 1) { s += __shfl_down(s, o); s2 += __shfl_down(s2, o); }
  __shared__ float rs[4], rs2[4];
  int w = threadIdx.x >> 6;
  if ((threadIdx.x & 63) == 0) { rs[w] = s; rs2[w] = s2; }
  __syncthreads();
  s  = rs[0] + rs[1] + rs[2] + rs[3];
  s2 = rs2[0] + rs2[1] + rs2[2] + rs2[3];
  float inv  = 1.f / (float)cols;
  float mean = s * inv;
  float var  = s2 * inv - mean * mean;
  float rstd = rsqrtf(var + 1e-5f);
  unsigned short* outp = out + (size_t)row * cols;
  for (int c = threadIdx.x * 4; c < cols; c += 1024) {
    float4 v = *(const float4*)(x + c);
    ushort4 ov;
    ov.x = f2b((v.x - mean) * rstd * g[c + 0] + b[c + 0]);
    ov.y = f2b((v.y - mean) * rstd * g[c + 1] + b[c + 1]);
    ov.z = f2b((v.z - mean) * rstd * g[c + 2] + b[c + 2]);
    ov.w = f2b((v.w - mean) * rstd * g[c + 3] + b[c + 3]);
    *(ushort4*)(outp + c) = ov;
  }
}

// ---------------------------------------------------------------------------
// 8-phase counted-vmcnt MFMA GEMM (T2+T3+T4+T5).  Tile BM x 256, BK=64,
// 8 waves (2M x 4N), per-wave output (BM/2) x 64.
// RES: 0=none, 1=f32, 2=bf16.  OUTBF: 1=bf16 out, 0=f32 out.
// Epilogue: acc -> per-wave 16x72 LDS patch -> vectorized coalesced stores
// (+ vectorized residual loads).  Patch lives in L[0]; safe because NT is
// even for every instantiation (final tile uses L[1]).
// ---------------------------------------------------------------------------
template <int BM, int BIAS, int GELU, int RES, int OUTBF>
__global__ __launch_bounds__(512) void gemm256(const unsigned short* __restrict__ A,
                                               const unsigned short* __restrict__ Bt,
                                               float* __restrict__ Cf,
                                               unsigned short* __restrict__ Cb,
                                               const float* __restrict__ bias,
                                               const float* __restrict__ resf,
                                               const unsigned short* __restrict__ resb,
                                               int M, int N, int K) {
  constexpr int MF = BM / 32;   // per-wave M frags (8 or 4)
  constexpr int MH = MF / 2;
  constexpr int LA = BM / 128;  // gload_lds per wave per A-half (2 or 1)
  __shared__ unsigned short L[2][(BM + 256) * 64];
  const int tid = threadIdx.x;
  const int w = tid >> 6, l = tid & 63;
  const int rl = l & 15, kb = l >> 4;
  const int wm = w >> 2, wn = w & 3;
  const int m0 = blockIdx.x * BM, n0 = blockIdx.y * 256;
  const int NT = K >> 6;
  const int colsw = ((l & 7) ^ (l >> 3)) * 8;  // pre-swizzled source granule
  const int lrow = l >> 3;

  // half: 0=B0(rows n0..+128), 1=B1, 2=A0(rows m0..+BM/2), 3=A1
  auto stage = [&](int t, int half) {
    if (t >= NT) return;
    unsigned short* base = L[t & 1];
    if (half < 2) {
      const unsigned short* g = Bt + (size_t)(n0 + half * 128) * K + t * 64;
#pragma unroll
      for (int j = 0; j < 2; ++j) {
        int row = w * 16 + j * 8;
        gload_lds16(g + (size_t)(row + lrow) * K + colsw,
                    base + BM * 64 + half * 8192 + row * 64);
      }
    } else {
      const int h = half - 2;
      const unsigned short* g = A + (size_t)(m0 + h * (BM / 2)) * K + t * 64;
#pragma unroll
      for (int j = 0; j < LA; ++j) {
        int row = w * (8 * LA) + j * 8;
        gload_lds16(g + (size_t)(row + lrow) * K + colsw,
                    base + h * (BM / 2) * 64 + row * 64);
      }
    }
  };

  f32x4 acc[MF][4];
  f32x4 zz = {0.f, 0.f, 0.f, 0.f};
#pragma unroll
  for (int i = 0; i < MF; ++i)
#pragma unroll
    for (int j = 0; j < 4; ++j) acc[i][j] = zz;

  // prologue: tile0 all 4 halves, tile1 first 3
  stage(0, 0); stage(0, 1); stage(0, 2); stage(0, 3);
  stage(1, 0); stage(1, 1); stage(1, 2);

  const int aoff = wm * (BM / 2) * 64;
  const int boff = BM * 64 + (wn >> 1) * 8192 + (wn & 1) * 64 * 64;

  for (int t = 0; t < NT; ++t) {
    const unsigned short* Lb = L[t & 1];
    // ---- gate: tile t fully landed; 3 halves (t+1/t+2) in flight ----
    if (t + 1 < NT) {
      if constexpr (LA == 2) asm volatile("s_waitcnt vmcnt(6)" ::: "memory");
      else                   asm volatile("s_waitcnt vmcnt(5)" ::: "memory");
    } else {
      asm volatile("s_waitcnt vmcnt(0)" ::: "memory");
    }
    __builtin_amdgcn_sched_barrier(0);
    bar();

    bf16x8 af[MH][2], bf[4][2];
    // ---- p1: read all B + lower A; stage (t+1).A1; MFMA q0 ----
#pragma unroll
    for (int mf = 0; mf < MH; ++mf)
#pragma unroll
      for (int kf = 0; kf < 2; ++kf)
        af[mf][kf] = *(const bf16x8*)(Lb + aoff + (mf * 16 + rl) * 64 +
                                      (((kf * 4 + kb) ^ (rl & 7)) * 8));
#pragma unroll
    for (int nf = 0; nf < 4; ++nf)
#pragma unroll
      for (int kf = 0; kf < 2; ++kf)
        bf[nf][kf] = *(const bf16x8*)(Lb + boff + (nf * 16 + rl) * 64 +
                                      (((kf * 4 + kb) ^ (rl & 7)) * 8));
    stage(t + 1, 3);
    WAIT_LGKM0;
    __builtin_amdgcn_s_setprio(1);
#pragma unroll
    for (int mf = 0; mf < MH; ++mf)
#pragma unroll
      for (int nf = 0; nf < 2; ++nf)
#pragma unroll
        for (int kf = 0; kf < 2; ++kf)
          acc[mf][nf] = __builtin_amdgcn_mfma_f32_16x16x32_bf16(af[mf][kf], bf[nf][kf], acc[mf][nf], 0, 0, 0);
    __builtin_amdgcn_s_setprio(0);
    bar();

    // ---- p2: stage (t+2).B0; MFMA q1 ----
    stage(t + 2, 0);
    __builtin_amdgcn_s_setprio(1);
#pragma unroll
    for (int mf = 0; mf < MH; ++mf)
#pragma unroll
      for (int nf = 2; nf < 4; ++nf)
#pragma unroll
        for (int kf = 0; kf < 2; ++kf)
          acc[mf][nf] = __builtin_amdgcn_mfma_f32_16x16x32_bf16(af[mf][kf], bf[nf][kf], acc[mf][nf], 0, 0, 0);
    __builtin_amdgcn_s_setprio(0);
    bar();

    // ---- p3: read upper A; stage (t+2).B1; MFMA q2 ----
#pragma unroll
    for (int mf = 0; mf < MH; ++mf)
#pragma unroll
      for (int kf = 0; kf < 2; ++kf)
        af[mf][kf] = *(const bf16x8*)(Lb + aoff + ((MH + mf) * 16 + rl) * 64 +
                                      (((kf * 4 + kb) ^ (rl & 7)) * 8));
    stage(t + 2, 1);
    WAIT_LGKM0;
    __builtin_amdgcn_s_setprio(1);
#pragma unroll
    for (int mf = 0; mf < MH; ++mf)
#pragma unroll
      for (int nf = 0; nf < 2; ++nf)
#pragma unroll
        for (int kf = 0; kf < 2; ++kf)
          acc[MH + mf][nf] = __builtin_amdgcn_mfma_f32_16x16x32_bf16(af[mf][kf], bf[nf][kf], acc[MH + mf][nf], 0, 0, 0);
    __builtin_amdgcn_s_setprio(0);
    bar();

    // ---- p4: stage (t+2).A0; MFMA q3 ----  (next gate's bar closes phase)
    stage(t + 2, 2);
    __builtin_amdgcn_s_setprio(1);
#pragma unroll
    for (int mf = 0; mf < MH; ++mf)
#pragma unroll
      for (int nf = 2; nf < 4; ++nf)
#pragma unroll
        for (int kf = 0; kf < 2; ++kf)
          acc[MH + mf][nf] = __builtin_amdgcn_mfma_f32_16x16x32_bf16(af[mf][kf], bf[nf][kf], acc[MH + mf][nf], 0, 0, 0);
    __builtin_amdgcn_s_setprio(0);
  }

  bar();  // all frag reads done; L[0] free for epilogue patches (NT even)

  // ---- epilogue: per-wave 16x72 patch in LDS, vectorized stores ----
  float bias_v[4];
  if (BIAS) {
#pragma unroll
    for (int nf = 0; nf < 4; ++nf) bias_v[nf] = bias[n0 + wn * 64 + nf * 16 + rl];
  }
  unsigned short* patch  = ((unsigned short*)L) + w * (16 * 72);
  float*          patchf = ((float*)L) + w * (16 * 72);

#pragma unroll
  for (int mf = 0; mf < MF; ++mf) {
#pragma unroll
    for (int nf = 0; nf < 4; ++nf) {
#pragma unroll
      for (int r = 0; r < 4; ++r) {
        float v = acc[mf][nf][r];
        if (BIAS) v += bias_v[nf];
        if (GELU) {
          float t2 = 1.5957691f * (v + 0.044715f * v * v * v);  // 2*z
          float e = __expf(fminf(t2, 60.f));
          v = v * e / (e + 1.f);
        }
        int prow = kb * 4 + r, pcol = nf * 16 + rl;
        if (OUTBF) patch[prow * 72 + pcol] = f2b(v);
        else       patchf[prow * 72 + pcol] = v;
      }
    }
    WAIT_LGKM0;  // patch writes visible to own wave before transpose read
    if (OUTBF) {
#pragma unroll
      for (int half = 0; half < 2; ++half) {
        int prow = half * 8 + (l >> 3);
        int pcol = (l & 7) * 8;
        s16x8 vv = *(const s16x8*)(patch + prow * 72 + pcol);
        int grow = m0 + wm * (BM / 2) + mf * 16 + prow;
        int gcol = n0 + wn * 64 + pcol;
        *(s16x8*)(Cb + (size_t)grow * N + gcol) = vv;
      }
    } else {
#pragma unroll
      for (int p = 0; p < 4; ++p) {
        int prow = p * 4 + (l >> 4);
        int pcol = (l & 15) * 4;
        float4 vv = *(const float4*)(patchf + prow * 72 + pcol);
        int grow = m0 + wm * (BM / 2) + mf * 16 + prow;
        int gcol = n0 + wn * 64 + pcol;
        if (RES == 1) {
          float4 rv = *(const float4*)(resf + (size_t)grow * N + gcol);
          vv.x += rv.x; vv.y += rv.y; vv.z += rv.z; vv.w += rv.w;
        }
        if (RES == 2) {
          ushort4 rv = *(const ushort4*)(resb + (size_t)grow * N + gcol);
          vv.x += b2f(rv.x); vv.y += b2f(rv.y); vv.z += b2f(rv.z); vv.w += b2f(rv.w);
        }
        *(float4*)(Cf + (size_t)grow * N + gcol) = vv;
      }
    }
    WAIT_LGKM0;  // reads done before next mf overwrites patch
  }
}

// ---------------------------------------------------------------------------
// MFMA flash attention.  K is read from the fused KV buffer (row stride
// kstride); V comes pre-transposed (8,1024,576).
// ---------------------------------------------------------------------------
__global__ __launch_bounds__(256) void attn_mfma(const unsigned short* __restrict__ Qb,
                                                 const unsigned short* __restrict__ Kb,
                                                 const unsigned short* __restrict__ Vtb,
                                                 unsigned short* __restrict__ Ob,
                                                 int kstride) {
  __shared__ unsigned short Qs[64 * 64];
  __shared__ unsigned short Ks[2][64 * 64];
  __shared__ unsigned short Vs[2][64 * 64];
  __shared__ unsigned short Ps[64 * 64];

  const int t = threadIdx.x, w = t >> 6, l = t & 63;
  const int b = blockIdx.z, h = blockIdx.y, q0 = blockIdx.x * 64;
  const int rl = l & 15, kb = l >> 4;

  auto stage64 = [&](unsigned short* lds, const unsigned short* g, int gstride) {
#pragma unroll
    for (int p = 0; p < 2; ++p) {
      int row = p * 32 + w * 8 + (l >> 3);
      const unsigned short* src = g + (size_t)row * gstride + (((l & 7) ^ (row & 7)) * 8);
      gload_lds16(src, lds + p * 2048 + w * 512);
    }
  };

  const unsigned short* Qg = Qb + ((size_t)(b * 1024 + q0) * 1024 + h * 64);
  auto Kg = [&](int kt) { return Kb + ((size_t)(b * 576 + kt * 64) * kstride + h * 64); };
  auto Vg = [&](int kt) { return Vtb + ((size_t)(b * 1024 + h * 64) * 576 + kt * 64); };

  stage64(Qs, Qg, 1024);
  stage64(Ks[0], Kg(0), kstride);
  stage64(Vs[0], Vg(0), 576);
  __syncthreads();

  bf16x8 qf[2];
  {
    int row = w * 16 + rl;
#pragma unroll
    for (int kf = 0; kf < 2; ++kf)
      qf[kf] = *(const bf16x8*)(Qs + row * 64 + (((kf * 4 + kb) ^ (row & 7)) * 8));
  }

  float m_run[4], l_run[4];
  f32x4 accO[4];
#pragma unroll
  for (int r = 0; r < 4; ++r) { m_run[r] = -1e30f; l_run[r] = 0.f; }
  f32x4 zz = {0.f, 0.f, 0.f, 0.f};
#pragma unroll
  for (int nf = 0; nf < 4; ++nf) accO[nf] = zz;

  for (int kt = 0; kt < 9; ++kt) {
    const int buf = kt & 1;
    if (kt + 1 < 9) {
      stage64(Ks[buf ^ 1], Kg(kt + 1), kstride);
      stage64(Vs[buf ^ 1], Vg(kt + 1), 576);
    }

    f32x4 accS[4];
#pragma unroll
    for (int nf = 0; nf < 4; ++nf) accS[nf] = zz;
#pragma unroll
    for (int nf = 0; nf < 4; ++nf) {
      int row = nf * 16 + rl;
#pragma unroll
      for (int kf = 0; kf < 2; ++kf) {
        bf16x8 kfrag = *(const bf16x8*)(Ks[buf] + row * 64 + (((kf * 4 + kb) ^ (row & 7)) * 8));
        accS[nf] = __builtin_amdgcn_mfma_f32_16x16x32_bf16(qf[kf], kfrag, accS[nf], 0, 0, 0);
      }
    }

    float sv[4][4];
#pragma unroll
    for (int nf = 0; nf < 4; ++nf)
#pragma unroll
      for (int r = 0; r < 4; ++r) sv[nf][r] = accS[nf][r] * 0.125f;

    float al[4];
#pragma unroll
    for (int r = 0; r < 4; ++r) {
      float mr = fmaxf(fmaxf(sv[0][r], sv[1][r]), fmaxf(sv[2][r], sv[3][r]));
#pragma unroll
      for (int xm = 1; xm < 16; xm <<= 1) mr = fmaxf(mr, __shfl_xor(mr, xm));
      float mn = fmaxf(m_run[r], mr);
      al[r] = __expf(m_run[r] - mn);
      m_run[r] = mn;
      float rs = 0.f;
#pragma unroll
      for (int nf = 0; nf < 4; ++nf) {
        sv[nf][r] = __expf(sv[nf][r] - mn);
        rs += sv[nf][r];
      }
#pragma unroll
      for (int xm = 1; xm < 16; xm <<= 1) rs += __shfl_xor(rs, xm);
      l_run[r] = l_run[r] * al[r] + rs;
    }

#pragma unroll
    for (int nf = 0; nf < 4; ++nf)
#pragma unroll
      for (int r = 0; r < 4; ++r) {
        int q = w * 16 + kb * 4 + r;
        int col = nf * 16 + rl;
        Ps[q * 64 + (col ^ ((q & 7) << 3))] = f2b(sv[nf][r]);
      }

#pragma unroll
    for (int nf = 0; nf < 4; ++nf)
#pragma unroll
      for (int r = 0; r < 4; ++r) accO[nf][r] *= al[r];

    asm volatile("s_waitcnt lgkmcnt(0)" ::: "memory");
    __builtin_amdgcn_sched_barrier(0);

    bf16x8 pf[2];
    {
      int row = w * 16 + rl;
#pragma unroll
      for (int kf = 0; kf < 2; ++kf)
        pf[kf] = *(const bf16x8*)(Ps + row * 64 + (((kf * 4 + kb) ^ (row & 7)) * 8));
    }
#pragma unroll
    for (int nf = 0; nf < 4; ++nf) {
      int row = nf * 16 + rl;
#pragma unroll
      for (int kf = 0; kf < 2; ++kf) {
        bf16x8 vfrag = *(const bf16x8*)(Vs[buf] + row * 64 + (((kf * 4 + kb) ^ (row & 7)) * 8));
        accO[nf] = __builtin_amdgcn_mfma_f32_16x16x32_bf16(pf[kf], vfrag, accO[nf], 0, 0, 0);
      }
    }

    __syncthreads();
  }

#pragma unroll
  for (int nf = 0; nf < 4; ++nf) {
#pragma unroll
    for (int r = 0; r < 4; ++r) {
      float o = accO[nf][r] / l_run[r];
      size_t qg = (size_t)(b * 1024 + q0 + w * 16 + kb * 4 + r);
      Ob[qg * 1024 + h * 64 + nf * 16 + rl] = f2b(o);
    }
  }
}

// ---------------------------------------------------------------------------
// Launch
// ---------------------------------------------------------------------------
extern "C" void kernel_launch(void* const* d_in, const int* in_sizes, int n_in,
                              void* d_out, int out_size, void* d_ws, size_t ws_size,
                              hipStream_t stream) {
  const float* grid_in = (const float*)d_in[0];
  const float* qpos    = (const float*)d_in[1];
  const float* Wq      = (const float*)d_in[2];
  const float* Wk      = (const float*)d_in[3];
  const float* Wv      = (const float*)d_in[4];
  const float* Wo      = (const float*)d_in[5];
  const float* g_grid  = (const float*)d_in[6];
  const float* b_grid  = (const float*)d_in[7];
  const float* g_q     = (const float*)d_in[8];
  const float* b_q     = (const float*)d_in[9];
  const float* g_mlp   = (const float*)d_in[10];
  const float* b_mlp   = (const float*)d_in[11];
  const float* W1      = (const float*)d_in[12];
  const float* b1      = (const float*)d_in[13];
  const float* W2      = (const float*)d_in[14];
  const float* b2      = (const float*)d_in[15];

  char* ws = (char*)d_ws;
  size_t off = 0;
  auto alloc = [&](size_t bytes) -> void* {
    void* p = ws + off;
    off = (off + bytes + 255) & ~(size_t)255;
    return p;
  };

  unsigned short* Wqt  = (unsigned short*)alloc((size_t)1024 * 512 * 2);
  unsigned short* Wkvt = (unsigned short*)alloc((size_t)2048 * 1024 * 2);  // [Wk^T ; Wv^T]
  unsigned short* Wot  = (unsigned short*)alloc((size_t)1024 * 1024 * 2);
  unsigned short* W1t  = (unsigned short*)alloc((size_t)4096 * 1024 * 2);
  unsigned short* W2t  = (unsigned short*)alloc((size_t)1024 * 4096 * 2);
  unsigned short* gn   = (unsigned short*)alloc((size_t)4608 * 1024 * 2);
  unsigned short* qn   = (unsigned short*)alloc((size_t)8192 * 512 * 2);
  unsigned short* KVb  = (unsigned short*)alloc((size_t)4608 * 2048 * 2);  // K|V interleaved
  unsigned short* Qbf  = (unsigned short*)alloc((size_t)8192 * 1024 * 2);
  unsigned short* atb  = (unsigned short*)alloc((size_t)8192 * 1024 * 2);
  float*          xf   = (float*)alloc((size_t)8192 * 1024 * 4);
  unsigned short* xnb  = (unsigned short*)alloc((size_t)8192 * 1024 * 2);
  unsigned short* hb   = (unsigned short*)alloc((size_t)8192 * 4096 * 2);
  unsigned short* Vtb  = hb;  // dead before W1 GEMM writes hb (stream-ordered)
  (void)ws_size; (void)in_sizes; (void)n_in; (void)out_size;

  // weight transposes (f32 -> bf16, N-major)
  transpose_w<<<dim3(32, 16), 256, 0, stream>>>(Wq, Wqt, 512, 1024);
  transpose_w<<<dim3(32, 32), 256, 0, stream>>>(Wk, Wkvt, 1024, 1024);
  transpose_w<<<dim3(32, 32), 256, 0, stream>>>(Wv, Wkvt + (size_t)1024 * 1024, 1024, 1024);
  transpose_w<<<dim3(32, 32), 256, 0, stream>>>(Wo, Wot, 1024, 1024);
  transpose_w<<<dim3(128, 32), 256, 0, stream>>>(W1, W1t, 1024, 4096);
  transpose_w<<<dim3(32, 128), 256, 0, stream>>>(W2, W2t, 4096, 1024);

  // layernorms
  ln_kernel<<<4608, 256, 0, stream>>>(grid_in, g_grid, b_grid, gn, 1024);
  ln_kernel<<<8192, 256, 0, stream>>>(qpos, g_q, b_q, qn, 512);

  // fused K|V projection: (4608 x 2048) = gn @ [Wk Wv]
  gemm256<128, 0, 0, 0, 1><<<dim3(36, 8), 512, 0, stream>>>(gn, Wkvt, nullptr, KVb, nullptr, nullptr, nullptr, 4608, 2048, 1024);
  // Q projection (bf16 only)
  gemm256<128, 0, 0, 0, 1><<<dim3(64, 4), 512, 0, stream>>>(qn, Wqt, nullptr, Qbf, nullptr, nullptr, nullptr, 8192, 1024, 512);

  // V transpose for PV B-operand (V half of KVb)
  transpose_v<<<dim3(9, 16, 8), 256, 0, stream>>>(KVb + 1024, Vtb, 2048);

  // attention (MFMA)
  attn_mfma<<<dim3(16, 16, 8), 256, 0, stream>>>(Qbf, KVb, Vtb, atb, 2048);

  // x = Q + attn @ Wo   (residual read as bf16)
  gemm256<128, 0, 0, 2, 0><<<dim3(64, 4), 512, 0, stream>>>(atb, Wot, xf, nullptr, nullptr, nullptr, Qbf, 8192, 1024, 1024);

  // MLP
  ln_kernel<<<8192, 256, 0, stream>>>(xf, g_mlp, b_mlp, xnb, 1024);
  gemm256<256, 1, 1, 0, 1><<<dim3(32, 16), 512, 0, stream>>>(xnb, W1t, nullptr, hb, b1, nullptr, nullptr, 8192, 4096, 1024);
  gemm256<128, 1, 0, 1, 0><<<dim3(64, 4), 512, 0, stream>>>(hb, W2t, (float*)d_out, nullptr, b2, xf, nullptr, 8192, 1024, 4096);
}